// Round 5
// baseline (312.393 us; speedup 1.0000x reference)
//
#include <hip/hip_runtime.h>
#include <hip/hip_bf16.h>
#include <math.h>

#define N_NODES 50000
#define N_EDGES 400000
#define HEADS 6
#define DIMS 32
#define FEAT 192
#define NEG_SLOPE 0.2f

typedef __attribute__((ext_vector_type(8))) short short8;
typedef __attribute__((ext_vector_type(4))) float f32x4;

__device__ __forceinline__ unsigned short f2bu(float f) {
    __hip_bfloat16 h = __float2bfloat16(f);
    unsigned short u; __builtin_memcpy(&u, &h, 2); return u;
}
__device__ __forceinline__ float bu2f(unsigned short u) {
    return __uint_as_float(((unsigned)u) << 16);
}

// ---------------- workspace layout (byte offsets) ----------------
#define XL_OFF    0            // ushort N*192 = 19,200,000
#define XR_OFF    19200000     // ushort N*192
#define WT_OFF    38400000     // short 384*192 = 147,456
#define BLR_OFF   38547456     // float 384
#define PAIR_OFF  38548992     // int2 E = 3,200,000
#define DEG_OFF   41748992     // int N = 200,000
#define WSUM_OFF  41948992     // float N = 200,000 (adjacent to deg: one memset)
#define SCAN_OFF  42148992     // int N
#define BSUM_OFF  42348992     // int 256
#define BOFF_OFF  42350016     // int 256
#define NB_SCAN ((N_NODES + 255) / 256)   // 196

// ---------------- count (atomics/edge) + fused weight pack ----------------
__global__ __launch_bounds__(256) void k_count(const int* __restrict__ ei,
                                               const float* __restrict__ ew,
                                               int* __restrict__ deg,
                                               float* __restrict__ wsum,
                                               const float* __restrict__ Wl,
                                               const float* __restrict__ Wr,
                                               const float* __restrict__ bl,
                                               const float* __restrict__ br,
                                               short* __restrict__ Wt,
                                               float* __restrict__ blr) {
    int e = blockIdx.x * blockDim.x + threadIdx.x;
    if (e < N_EDGES) {
        int d = ei[N_EDGES + e];
        atomicAdd(&deg[d], 1);
        unsafeAtomicAdd(&wsum[d], ew[e]);   // incoming weight sum (for self-loop mean)
    }
    if (e < 384 * FEAT) {   // pack Wt[n][k] = W[k][n] (bf16)
        int n = e / FEAT, k = e - n * FEAT;
        float v = (n < FEAT) ? Wl[k * FEAT + n] : Wr[k * FEAT + (n - FEAT)];
        Wt[n * FEAT + k] = (short)f2bu(v);
    }
    if (e < 384) blr[e] = (e < FEAT) ? bl[e] : br[e - FEAT];
}

__global__ __launch_bounds__(256) void k_scan1(const int* __restrict__ deg,
                                               int* __restrict__ scan,
                                               int* __restrict__ bsums) {
    int t = threadIdx.x;
    int i = blockIdx.x * 256 + t;
    int v = (i < N_NODES) ? deg[i] : 0;
    __shared__ int s[256];
    s[t] = v; __syncthreads();
    for (int off = 1; off < 256; off <<= 1) {
        int u = (t >= off) ? s[t - off] : 0;
        __syncthreads();
        s[t] += u;
        __syncthreads();
    }
    if (i < N_NODES) scan[i] = s[t];   // inclusive within block
    if (t == 255) bsums[blockIdx.x] = s[255];
}

__global__ __launch_bounds__(256) void k_scan2(int* __restrict__ bsums,
                                               int* __restrict__ boffs) {
    int t = threadIdx.x;
    int v = (t < NB_SCAN) ? bsums[t] : 0;
    __shared__ int s[256];
    s[t] = v; __syncthreads();
    for (int off = 1; off < 256; off <<= 1) {
        int u = (t >= off) ? s[t - off] : 0;
        __syncthreads();
        s[t] += u;
        __syncthreads();
    }
    boffs[t] = s[t] - v;   // exclusive block offsets
}

// ---------------- fused scatter + MFMA GEMM (block-range split) ----------------
#define SCAT_BLOCKS ((N_EDGES + 383) / 384)   // 1042
#define GEMM_BLOCKS (N_NODES / 16)            // 3125
#define OSTRIDE 392
#define ASTRIDE 200
__global__ __launch_bounds__(384) void k_scatgemm(const int* __restrict__ ei,
                                                  const float* __restrict__ ew,
                                                  const int* __restrict__ scan,
                                                  const int* __restrict__ boffs,
                                                  int* __restrict__ deg,
                                                  int2* __restrict__ pair,
                                                  const float* __restrict__ x,
                                                  const short* __restrict__ Wt,
                                                  const float* __restrict__ blr,
                                                  unsigned short* __restrict__ xl,
                                                  unsigned short* __restrict__ xr) {
    __shared__ unsigned short sOut[16 * OSTRIDE];
    __shared__ unsigned short sA[16 * ASTRIDE];
    if (blockIdx.x < SCAT_BLOCKS) {
        int e = blockIdx.x * 384 + threadIdx.x;
        if (e < N_EDGES) {
            int d = ei[N_EDGES + e];
            int inclEnd = boffs[d >> 8] + scan[d];
            int old = atomicSub(&deg[d], 1);     // old in [1, deg]
            int2 p; p.x = ei[e]; p.y = __float_as_int(ew[e]);
            pair[inclEnd - old] = p;
        }
        return;
    }
    size_t row0 = (size_t)(blockIdx.x - SCAT_BLOCKS) * 16;

    {
        int q = threadIdx.x;
        int row = q / 24, k0 = (q - row * 24) * 8;
        const float* ap = x + (row0 + row) * FEAT + k0;
        float4 v0 = *(const float4*)ap;
        float4 v1 = *(const float4*)(ap + 4);
        unsigned short tmp[8];
        tmp[0] = f2bu(v0.x); tmp[1] = f2bu(v0.y); tmp[2] = f2bu(v0.z); tmp[3] = f2bu(v0.w);
        tmp[4] = f2bu(v1.x); tmp[5] = f2bu(v1.y); tmp[6] = f2bu(v1.z); tmp[7] = f2bu(v1.w);
        int kw = (k0 >> 1) ^ ((row & 7) << 2);
        *(uint4*)&sA[row * ASTRIDE + kw * 2] = *(const uint4*)tmp;
    }
    __syncthreads();

    int wv   = threadIdx.x >> 6;
    int lane = threadIdx.x & 63;
    int m    = lane & 15;
    int kg   = lane >> 4;
    int ncol0 = wv * 64;

    f32x4 acc0 = {0.f,0.f,0.f,0.f}, acc1 = acc0, acc2 = acc0, acc3 = acc0;

#pragma unroll
    for (int ks = 0; ks < 6; ks++) {
        int kb = ks * 32 + kg * 8;
        int kw = (kb >> 1) ^ ((m & 7) << 2);
        short8 af = *(const short8*)&sA[m * ASTRIDE + kw * 2];
        const short* wp = Wt + (size_t)(ncol0 + m) * FEAT + kb;
        short8 b0 = *(const short8*)(wp);
        short8 b1 = *(const short8*)(wp + 16 * FEAT);
        short8 b2 = *(const short8*)(wp + 32 * FEAT);
        short8 b3 = *(const short8*)(wp + 48 * FEAT);
        acc0 = __builtin_amdgcn_mfma_f32_16x16x32_bf16(af, b0, acc0, 0, 0, 0);
        acc1 = __builtin_amdgcn_mfma_f32_16x16x32_bf16(af, b1, acc1, 0, 0, 0);
        acc2 = __builtin_amdgcn_mfma_f32_16x16x32_bf16(af, b2, acc2, 0, 0, 0);
        acc3 = __builtin_amdgcn_mfma_f32_16x16x32_bf16(af, b3, acc3, 0, 0, 0);
    }

    f32x4 accs[4] = {acc0, acc1, acc2, acc3};
#pragma unroll
    for (int t4 = 0; t4 < 4; t4++) {
        int cc = ncol0 + t4 * 16 + m;
        float bv = blr[cc];
#pragma unroll
        for (int r = 0; r < 4; r++) {
            sOut[(kg * 4 + r) * OSTRIDE + cc] = f2bu(accs[t4][r] + bv);
        }
    }
    __syncthreads();
    for (int q = threadIdx.x; q < 768; q += 384) {
        int row = q / 48, p = q - row * 48;
        uint4 v = *(const uint4*)&sOut[row * OSTRIDE + p * 8];
        if (p < 24) *(uint4*)(xl + (row0 + row) * FEAT + p * 8) = v;
        else        *(uint4*)(xr + (row0 + row) * FEAT + (p - 24) * 8) = v;
    }
}

// ---------------- fused node kernel: MFMA segment-sum accumulate ----------------
// 8 nodes/block. Per 32-edge chunk, the weighted segment-sum
//   acc[nn][ch] = sum_i (dst_i==nn) * ex[i][h] * xl[src_i][ch]
// is computed as one-hot MFMA per head: A_h[16x32] (rows=nodes, k=edges,
// value = ex split hi+lo bf16) x B[32xch]. den comes free via B=ones.
// This removes the per-edge LDS-latency-serialized loops (~130cy/edge).
// Fragment conventions identical to k_scatgemm (verified on this harness).
#define NPB 8
#define CEDGE 32
#define RS 100   // uints per row; rows 16B aligned; 100 % 32 = 4 spreads banks
#define APAD 36  // att/We row stride (float4-aligned)
#define ACS 196  // float stride of sAcc dump (aliased over sXL)
__global__ __launch_bounds__(192) void k_node(const float* __restrict__ x,
                                              const float* __restrict__ bias,
                                              const float* __restrict__ att,
                                              const float* __restrict__ We,
                                              const int* __restrict__ scan,
                                              const int* __restrict__ boffs,
                                              const float* __restrict__ wsum,
                                              const int2* __restrict__ pair,
                                              const unsigned short* __restrict__ xl,
                                              const unsigned short* __restrict__ xr,
                                              float* __restrict__ out) {
    __shared__ __align__(16) unsigned int sXL[CEDGE * RS];   // reused as sAcc post-loop
    __shared__ __align__(16) unsigned int sXR[NPB * RS];
    __shared__ float sEx[CEDGE * HEADS];
    __shared__ float sExS[NPB * HEADS];
    __shared__ int   sSrc[2][CEDGE];
    __shared__ float sW[2][CEDGE];
    __shared__ int   sDst[2][CEDGE];
    __shared__ int   sStart[NPB + 1];
    __shared__ __align__(16) float sAttP[HEADS * APAD];
    __shared__ __align__(16) float sWeP[HEADS * APAD];
    __shared__ float sDen[NPB * HEADS];

    int t = threadIdx.x;
    int h = t >> 5;                  // head for channel role (epilogue)
    int lane = t & 63;
    int wv = t >> 6;                 // wave 0..2 -> heads {2wv, 2wv+1}
    int n0 = blockIdx.x * NPB;

    // per-thread gbase/etot (uniform -> scalar loads); enables pre-sync pair load
    int gbase = boffs[n0 >> 8] + ((n0 & 255) ? scan[n0 - 1] : 0);
    int n8 = n0 + NPB;
    int gend = (n8 >= N_NODES) ? N_EDGES
             : (boffs[n8 >> 8] + ((n8 & 255) ? scan[n8 - 1] : 0));
    int etot = gend - gbase;
    int c0 = min(etot, CEDGE);

    // chunk-0 pair -> sSrc[0]/sW[0] (pre-sync)
    if (t < c0) { int2 p = pair[gbase + t]; sSrc[0][t] = p.x; sW[0][t] = __int_as_float(p.y); }

    for (int q = t; q < HEADS * APAD; q += 192) {
        int hh = q / APAD, c = q - hh * APAD;
        if (c < 32) { sAttP[q] = att[hh * 32 + c]; sWeP[q] = We[hh * 32 + c]; }
    }
    if (t <= NPB) {
        int n = n0 + t;
        int st;
        if (n >= N_NODES) st = N_EDGES;
        else {
            int b = n >> 8;
            st = boffs[b] + ((n & 255) ? scan[n - 1] : 0);
        }
        sStart[t] = st;
    }
    if (t < NPB) {   // sDst[0] pre-fill with self-computed bounds (no sStart dep)
        int n = n0 + t;
        int a = boffs[n >> 8] + ((n & 255) ? scan[n - 1] : 0);
        int n1 = n + 1;
        int b = (n1 >= N_NODES) ? N_EDGES
              : (boffs[n1 >> 8] + ((n1 & 255) ? scan[n1 - 1] : 0));
        int lo = a - gbase; if (lo < 0) lo = 0;
        int hi = b - gbase; if (hi > c0) hi = c0;
        for (int q = lo; q < hi; q++) sDst[0][q] = t;
    }
    {   // stage this block's 8 xr rows: 192 = 8 rows x 24 uint4
        int nn = t / 24, p = t - nn * 24;
        *(uint4*)&sXR[nn * RS + p * 4] = ((const uint4*)(xr + (size_t)(n0 + nn) * FEAT))[p];
    }
    __syncthreads();

    // MFMA accumulators: per wave, 2 heads x {2 channel tiles + den}
    f32x4 zz = {0.f,0.f,0.f,0.f};
    f32x4 cA0 = zz, cA1 = zz, cB0 = zz, cB1 = zz, dA = zz, dB = zz;
    short8 kOnes;
#pragma unroll
    for (int j = 0; j < 8; j++) kOnes[j] = (short)0x3F80;   // bf16 1.0

    int nnD = t / HEADS, hhD = t - nnD * HEADS;   // self-loop ownership (t < 48)

    int nch = (etot + CEDGE - 1) / CEDGE;
    for (int ci = 0; ci < nch; ci++) {
        int i0 = ci * CEDGE;
        int c  = min(etot - i0, CEDGE);
        int cn = min(etot - i0 - CEDGE, CEDGE);   // next chunk size
        int cb = ci & 1, nb = cb ^ 1;

        // A: gather xl chunk ci -> sXL; overlap: prefetch pair ci+1 -> regs; fill sDst[nb]
        {
            int nld = c * 24;
#pragma unroll
            for (int s = 0; s < 4; s++) {
                int q = t + s * 192;
                if (q < nld) {
                    int i = q / 24, p = q - i * 24;
                    *(uint4*)&sXL[i * RS + p * 4] =
                        *(const uint4*)(xl + (size_t)sSrc[cb][i] * FEAT + p * 8);
                }
            }
        }
        int2 P;
        if (t < cn) P = pair[gbase + i0 + CEDGE + t];
        if (t < NPB && cn > 0) {
            int lo = sStart[t] - gbase - i0 - CEDGE;     if (lo < 0) lo = 0;
            int hi = sStart[t + 1] - gbase - i0 - CEDGE; if (hi > cn) hi = cn;
            for (int q = lo; q < hi; q++) sDst[nb][q] = t;
        }
        __syncthreads();

        // C: alpha + exp for chunk ci; commit pair regs -> sSrc/sW[nb]
        if (t < c * HEADS) {
            int i = t / HEADS, hh = t - i * HEADS;
            int nn = sDst[cb][i];
            float w = sW[cb][i];
            const uint4* pa = (const uint4*)&sXL[i * RS + hh * 16];
            const uint4* pb = (const uint4*)&sXR[nn * RS + hh * 16];
            float alpha = 0.f;
#pragma unroll
            for (int g = 0; g < 4; g++) {
                uint4 a4 = pa[g];
                uint4 b4 = pb[g];
                float4 we0 = *(const float4*)&sWeP[hh * APAD + g * 8];
                float4 we1 = *(const float4*)&sWeP[hh * APAD + g * 8 + 4];
                float4 at0 = *(const float4*)&sAttP[hh * APAD + g * 8];
                float4 at1 = *(const float4*)&sAttP[hh * APAD + g * 8 + 4];
                float wec[8] = {we0.x, we0.y, we0.z, we0.w, we1.x, we1.y, we1.z, we1.w};
                float atc[8] = {at0.x, at0.y, at0.z, at0.w, at1.x, at1.y, at1.z, at1.w};
                unsigned aw[4] = {a4.x, a4.y, a4.z, a4.w};
                unsigned bw[4] = {b4.x, b4.y, b4.z, b4.w};
#pragma unroll
                for (int q = 0; q < 4; q++) {
                    float m0 = bu2f((unsigned short)aw[q]) + bu2f((unsigned short)bw[q]) + w * wec[q * 2];
                    m0 = fmaxf(m0, NEG_SLOPE * m0);
                    alpha += m0 * atc[q * 2];
                    float m1 = bu2f((unsigned short)(aw[q] >> 16)) + bu2f((unsigned short)(bw[q] >> 16)) + w * wec[q * 2 + 1];
                    m1 = fmaxf(m1, NEG_SLOPE * m1);
                    alpha += m1 * atc[q * 2 + 1];
                }
            }
            sEx[t] = __expf(alpha);
        }
        if (t < cn) { sSrc[nb][t] = P.x; sW[nb][t] = __int_as_float(P.y); }
        __syncthreads();

        // E: MFMA segment-sum accumulate (per wave: 2 heads)
        {
            const unsigned short* xlu = (const unsigned short*)sXL;
            int g8 = (lane >> 4) * 8;   // k-base of this lane's 8 elements
            int r  = lane & 15;         // A row / B col / D col
#pragma unroll
            for (int hid = 0; hid < 2; hid++) {
                int hh = wv * 2 + hid;
                short8 aHi, aLo, b0, b1;
#pragma unroll
                for (int j = 0; j < 8; j++) {
                    int i = g8 + j;
                    bool ok = (i < c);
                    float ex = ok ? sEx[i * HEADS + hh] : 0.f;
                    int dd = sDst[cb][i];               // in-bounds; gated by ex/b below
                    unsigned short exHi = f2bu(ex);
                    unsigned short exLo = f2bu(ex - bu2f(exHi));
                    bool own = ok && (dd == r);
                    aHi[j] = own ? (short)exHi : (short)0;
                    aLo[j] = own ? (short)exLo : (short)0;
                    int ub = i * (RS * 2) + hh * 32 + r;
                    b0[j] = ok ? (short)xlu[ub] : (short)0;
                    b1[j] = ok ? (short)xlu[ub + 16] : (short)0;
                }
                if (hid == 0) {
                    cA0 = __builtin_amdgcn_mfma_f32_16x16x32_bf16(aHi, b0, cA0, 0, 0, 0);
                    cA0 = __builtin_amdgcn_mfma_f32_16x16x32_bf16(aLo, b0, cA0, 0, 0, 0);
                    cA1 = __builtin_amdgcn_mfma_f32_16x16x32_bf16(aHi, b1, cA1, 0, 0, 0);
                    cA1 = __builtin_amdgcn_mfma_f32_16x16x32_bf16(aLo, b1, cA1, 0, 0, 0);
                    dA  = __builtin_amdgcn_mfma_f32_16x16x32_bf16(aHi, kOnes, dA, 0, 0, 0);
                    dA  = __builtin_amdgcn_mfma_f32_16x16x32_bf16(aLo, kOnes, dA, 0, 0, 0);
                } else {
                    cB0 = __builtin_amdgcn_mfma_f32_16x16x32_bf16(aHi, b0, cB0, 0, 0, 0);
                    cB0 = __builtin_amdgcn_mfma_f32_16x16x32_bf16(aLo, b0, cB0, 0, 0, 0);
                    cB1 = __builtin_amdgcn_mfma_f32_16x16x32_bf16(aHi, b1, cB1, 0, 0, 0);
                    cB1 = __builtin_amdgcn_mfma_f32_16x16x32_bf16(aLo, b1, cB1, 0, 0, 0);
                    dB  = __builtin_amdgcn_mfma_f32_16x16x32_bf16(aHi, kOnes, dB, 0, 0, 0);
                    dB  = __builtin_amdgcn_mfma_f32_16x16x32_bf16(aLo, kOnes, dB, 0, 0, 0);
                }
            }
        }
        __syncthreads();   // protects sXL/sDst overwrite next iter
    }

    // dump MFMA accumulators: sAcc (aliased over sXL) + sDen
    {
        float* sAcc = (float*)sXL;
        int rowg = lane >> 4;          // D row group
        int cc   = lane & 15;          // D col
        if (rowg < 2) {                // rows 0..7 = the 8 nodes
#pragma unroll
            for (int rg = 0; rg < 4; rg++) {
                int nn = rowg * 4 + rg;
                int h0 = wv * 2, h1 = wv * 2 + 1;
                sAcc[nn * ACS + h0 * 32 + cc]      = cA0[rg];
                sAcc[nn * ACS + h0 * 32 + 16 + cc] = cA1[rg];
                sAcc[nn * ACS + h1 * 32 + cc]      = cB0[rg];
                sAcc[nn * ACS + h1 * 32 + 16 + cc] = cB1[rg];
                if (cc == 0) {
                    sDen[nn * HEADS + h0] = dA[rg];
                    sDen[nn * HEADS + h1] = dB[rg];
                }
            }
        }
    }

    // self-loop alpha (w = mean incoming weight); self xl row read from GLOBAL (L3-warm)
    if (t < NPB * HEADS) {
        int nn = nnD, hh = hhD;
        int dg = sStart[nn + 1] - sStart[nn];
        float w = wsum[n0 + nn] / fmaxf((float)dg, 1.0f);
        const uint4* pa = (const uint4*)(xl + (size_t)(n0 + nn) * FEAT + hh * 32);
        const uint4* pb = (const uint4*)&sXR[nn * RS + hh * 16];
        float alpha = 0.f;
#pragma unroll
        for (int g = 0; g < 4; g++) {
            uint4 a4 = pa[g];
            uint4 b4 = pb[g];
            float4 we0 = *(const float4*)&sWeP[hh * APAD + g * 8];
            float4 we1 = *(const float4*)&sWeP[hh * APAD + g * 8 + 4];
            float4 at0 = *(const float4*)&sAttP[hh * APAD + g * 8];
            float4 at1 = *(const float4*)&sAttP[hh * APAD + g * 8 + 4];
            float wec[8] = {we0.x, we0.y, we0.z, we0.w, we1.x, we1.y, we1.z, we1.w};
            float atc[8] = {at0.x, at0.y, at0.z, at0.w, at1.x, at1.y, at1.z, at1.w};
            unsigned aw[4] = {a4.x, a4.y, a4.z, a4.w};
            unsigned bw[4] = {b4.x, b4.y, b4.z, b4.w};
#pragma unroll
            for (int q = 0; q < 4; q++) {
                float m0 = bu2f((unsigned short)aw[q]) + bu2f((unsigned short)bw[q]) + w * wec[q * 2];
                m0 = fmaxf(m0, NEG_SLOPE * m0);
                alpha += m0 * atc[q * 2];
                float m1 = bu2f((unsigned short)(aw[q] >> 16)) + bu2f((unsigned short)(bw[q] >> 16)) + w * wec[q * 2 + 1];
                m1 = fmaxf(m1, NEG_SLOPE * m1);
                alpha += m1 * atc[q * 2 + 1];
            }
        }
        sExS[t] = __expf(alpha);
    }
    __syncthreads();

    // epilogue: self-loop add, divide, residual + bias + relu (self xl from global)
    {
        const float* sAcc = (const float*)sXL;
        float bj = bias[t];
        float accv[NPB];
#pragma unroll
        for (int nn = 0; nn < NPB; nn++) accv[nn] = sAcc[nn * ACS + t];
#pragma unroll
        for (int nn = 0; nn < NPB; nn++) {
            float exS = sExS[nn * HEADS + h];
            size_t off = (size_t)(n0 + nn) * FEAT + t;
            float xsv = bu2f(xl[off]);
            float num = accv[nn] + exS * xsv;
            float dn  = sDen[nn * HEADS + h] + exS;
            float val = x[off] + bj + num / dn;
            out[off] = (val > 0.f) ? val : 0.f;
        }
    }
}

extern "C" void kernel_launch(void* const* d_in, const int* in_sizes, int n_in,
                              void* d_out, int out_size, void* d_ws, size_t ws_size,
                              hipStream_t stream) {
    const float* x    = (const float*)d_in[0];
    const int*   ei   = (const int*)d_in[1];
    const float* ew   = (const float*)d_in[2];
    const float* Wl   = (const float*)d_in[3];
    const float* bl   = (const float*)d_in[4];
    const float* Wr   = (const float*)d_in[5];
    const float* br   = (const float*)d_in[6];
    const float* We   = (const float*)d_in[7];
    const float* att  = (const float*)d_in[8];
    const float* bias = (const float*)d_in[9];
    float* out = (float*)d_out;

    char* ws = (char*)d_ws;
    unsigned short* xl = (unsigned short*)(ws + XL_OFF);
    unsigned short* xr = (unsigned short*)(ws + XR_OFF);
    short* Wt     = (short*)(ws + WT_OFF);
    float* blr    = (float*)(ws + BLR_OFF);
    int2*  pair   = (int2*)(ws + PAIR_OFF);
    int*   deg    = (int*)(ws + DEG_OFF);
    float* wsum   = (float*)(ws + WSUM_OFF);
    int*   scan   = (int*)(ws + SCAN_OFF);
    int*   bsums  = (int*)(ws + BSUM_OFF);
    int*   boffs  = (int*)(ws + BOFF_OFF);

    // zero deg + wsum (adjacent); harness poisons ws with 0xAA
    hipMemsetAsync(ws + DEG_OFF, 0, 2 * N_NODES * sizeof(int), stream);

    k_count<<<(N_EDGES + 255) / 256, 256, 0, stream>>>(ei, ew, deg, wsum, Wl, Wr, bl, br, Wt, blr);
    k_scan1<<<NB_SCAN, 256, 0, stream>>>(deg, scan, bsums);
    k_scan2<<<1, 256, 0, stream>>>(bsums, boffs);

    k_scatgemm<<<SCAT_BLOCKS + GEMM_BLOCKS, 384, 0, stream>>>(ei, ew, scan, boffs, deg,
                                                              pair, x, Wt, blr, xl, xr);

    k_node<<<N_NODES / NPB, 192, 0, stream>>>(x, bias, att, We, scan, boffs, wsum,
                                              pair, xl, xr, out);
}

// Round 6
// 294.973 us; speedup vs baseline: 1.0591x; 1.0591x over previous
//
#include <hip/hip_runtime.h>
#include <hip/hip_bf16.h>
#include <math.h>

#define N_NODES 50000
#define N_EDGES 400000
#define HEADS 6
#define DIMS 32
#define FEAT 192
#define NEG_SLOPE 0.2f

typedef __attribute__((ext_vector_type(8))) short short8;
typedef __attribute__((ext_vector_type(4))) float f32x4;

__device__ __forceinline__ unsigned short f2bu(float f) {
    __hip_bfloat16 h = __float2bfloat16(f);
    unsigned short u; __builtin_memcpy(&u, &h, 2); return u;
}
__device__ __forceinline__ float bu2f(unsigned short u) {
    return __uint_as_float(((unsigned)u) << 16);
}

// ---------------- workspace layout (byte offsets) ----------------
#define XL_OFF    0            // ushort N*192 = 19,200,000
#define XR_OFF    19200000     // ushort N*192
#define WT_OFF    38400000     // short 384*192 = 147,456
#define BLR_OFF   38547456     // float 384
#define PAIR_OFF  38548992     // int2 E = 3,200,000
#define DEG_OFF   41748992     // int N = 200,000
#define SCAN_OFF  42148992     // int N
#define BSUM_OFF  42348992     // int 256
#define BOFF_OFF  42350016     // int 256
#define NB_SCAN ((N_NODES + 255) / 256)   // 196

// ---------------- count (1 atomic/edge) + fused weight pack ----------------
__global__ __launch_bounds__(256) void k_count(const int* __restrict__ ei,
                                               int* __restrict__ deg,
                                               const float* __restrict__ Wl,
                                               const float* __restrict__ Wr,
                                               const float* __restrict__ bl,
                                               const float* __restrict__ br,
                                               short* __restrict__ Wt,
                                               float* __restrict__ blr) {
    int e = blockIdx.x * blockDim.x + threadIdx.x;
    if (e < N_EDGES) atomicAdd(&deg[ei[N_EDGES + e]], 1);
    if (e < 384 * FEAT) {   // pack Wt[n][k] = W[k][n] (bf16)
        int n = e / FEAT, k = e - n * FEAT;
        float v = (n < FEAT) ? Wl[k * FEAT + n] : Wr[k * FEAT + (n - FEAT)];
        Wt[n * FEAT + k] = (short)f2bu(v);
    }
    if (e < 384) blr[e] = (e < FEAT) ? bl[e] : br[e - FEAT];
}

__global__ __launch_bounds__(256) void k_scan1(const int* __restrict__ deg,
                                               int* __restrict__ scan,
                                               int* __restrict__ bsums) {
    int t = threadIdx.x;
    int i = blockIdx.x * 256 + t;
    int v = (i < N_NODES) ? deg[i] : 0;
    __shared__ int s[256];
    s[t] = v; __syncthreads();
    for (int off = 1; off < 256; off <<= 1) {
        int u = (t >= off) ? s[t - off] : 0;
        __syncthreads();
        s[t] += u;
        __syncthreads();
    }
    if (i < N_NODES) scan[i] = s[t];   // inclusive within block
    if (t == 255) bsums[blockIdx.x] = s[255];
}

__global__ __launch_bounds__(256) void k_scan2(int* __restrict__ bsums,
                                               int* __restrict__ boffs) {
    int t = threadIdx.x;
    int v = (t < NB_SCAN) ? bsums[t] : 0;
    __shared__ int s[256];
    s[t] = v; __syncthreads();
    for (int off = 1; off < 256; off <<= 1) {
        int u = (t >= off) ? s[t - off] : 0;
        __syncthreads();
        s[t] += u;
        __syncthreads();
    }
    boffs[t] = s[t] - v;   // exclusive block offsets
}

// ---------------- fused scatter + MFMA GEMM (block-range split) ----------------
#define SCAT_BLOCKS ((N_EDGES + 383) / 384)   // 1042
#define GEMM_BLOCKS (N_NODES / 16)            // 3125
#define OSTRIDE 392
#define ASTRIDE 200
__global__ __launch_bounds__(384) void k_scatgemm(const int* __restrict__ ei,
                                                  const float* __restrict__ ew,
                                                  const int* __restrict__ scan,
                                                  const int* __restrict__ boffs,
                                                  int* __restrict__ deg,
                                                  int2* __restrict__ pair,
                                                  const float* __restrict__ x,
                                                  const short* __restrict__ Wt,
                                                  const float* __restrict__ blr,
                                                  unsigned short* __restrict__ xl,
                                                  unsigned short* __restrict__ xr) {
    __shared__ unsigned short sOut[16 * OSTRIDE];
    __shared__ unsigned short sA[16 * ASTRIDE];
    if (blockIdx.x < SCAT_BLOCKS) {
        int e = blockIdx.x * 384 + threadIdx.x;
        if (e < N_EDGES) {
            int d = ei[N_EDGES + e];
            int inclEnd = boffs[d >> 8] + scan[d];
            int old = atomicSub(&deg[d], 1);     // old in [1, deg]
            int2 p; p.x = ei[e]; p.y = __float_as_int(ew[e]);
            pair[inclEnd - old] = p;
        }
        return;
    }
    size_t row0 = (size_t)(blockIdx.x - SCAT_BLOCKS) * 16;

    {
        int q = threadIdx.x;
        int row = q / 24, k0 = (q - row * 24) * 8;
        const float* ap = x + (row0 + row) * FEAT + k0;
        float4 v0 = *(const float4*)ap;
        float4 v1 = *(const float4*)(ap + 4);
        unsigned short tmp[8];
        tmp[0] = f2bu(v0.x); tmp[1] = f2bu(v0.y); tmp[2] = f2bu(v0.z); tmp[3] = f2bu(v0.w);
        tmp[4] = f2bu(v1.x); tmp[5] = f2bu(v1.y); tmp[6] = f2bu(v1.z); tmp[7] = f2bu(v1.w);
        int kw = (k0 >> 1) ^ ((row & 7) << 2);
        *(uint4*)&sA[row * ASTRIDE + kw * 2] = *(const uint4*)tmp;
    }
    __syncthreads();

    int wv   = threadIdx.x >> 6;
    int lane = threadIdx.x & 63;
    int m    = lane & 15;
    int kg   = lane >> 4;
    int ncol0 = wv * 64;

    f32x4 acc0 = {0.f,0.f,0.f,0.f}, acc1 = acc0, acc2 = acc0, acc3 = acc0;

#pragma unroll
    for (int ks = 0; ks < 6; ks++) {
        int kb = ks * 32 + kg * 8;
        int kw = (kb >> 1) ^ ((m & 7) << 2);
        short8 af = *(const short8*)&sA[m * ASTRIDE + kw * 2];
        const short* wp = Wt + (size_t)(ncol0 + m) * FEAT + kb;
        short8 b0 = *(const short8*)(wp);
        short8 b1 = *(const short8*)(wp + 16 * FEAT);
        short8 b2 = *(const short8*)(wp + 32 * FEAT);
        short8 b3 = *(const short8*)(wp + 48 * FEAT);
        acc0 = __builtin_amdgcn_mfma_f32_16x16x32_bf16(af, b0, acc0, 0, 0, 0);
        acc1 = __builtin_amdgcn_mfma_f32_16x16x32_bf16(af, b1, acc1, 0, 0, 0);
        acc2 = __builtin_amdgcn_mfma_f32_16x16x32_bf16(af, b2, acc2, 0, 0, 0);
        acc3 = __builtin_amdgcn_mfma_f32_16x16x32_bf16(af, b3, acc3, 0, 0, 0);
    }

    f32x4 accs[4] = {acc0, acc1, acc2, acc3};
#pragma unroll
    for (int t4 = 0; t4 < 4; t4++) {
        int cc = ncol0 + t4 * 16 + m;
        float bv = blr[cc];
#pragma unroll
        for (int r = 0; r < 4; r++) {
            sOut[(kg * 4 + r) * OSTRIDE + cc] = f2bu(accs[t4][r] + bv);
        }
    }
    __syncthreads();
    for (int q = threadIdx.x; q < 768; q += 384) {
        int row = q / 48, p = q - row * 48;
        uint4 v = *(const uint4*)&sOut[row * OSTRIDE + p * 8];
        if (p < 24) *(uint4*)(xl + (row0 + row) * FEAT + p * 8) = v;
        else        *(uint4*)(xr + (row0 + row) * FEAT + (p - 24) * 8) = v;
    }
}

// ---------------- fused node kernel: MFMA segment-sum, <=64 VGPR ----------------
// 8 nodes/block. E-phase: one-hot MFMA per head (A = ex hi+lo bf16, packed in
// phase C); den and wsm are lane-partial f32 registers accumulated during the
// fragment build and shfl-reduced at dump (no den MFMAs, no kOnes, no global
// wsum atomics). __launch_bounds__(192,8) pins VGPR <= 64 (m69 occupancy cliff).
#define NPB 8
#define CEDGE 32
#define RS 100   // uints per row; rows 16B aligned; 100 % 32 = 4 spreads banks
#define APAD 36  // att/We row stride (float4-aligned)
#define ACS 196  // float stride of sAcc dump (aliased over sXL)
__global__ __launch_bounds__(192, 8) void k_node(const float* __restrict__ x,
                                              const float* __restrict__ bias,
                                              const float* __restrict__ att,
                                              const float* __restrict__ We,
                                              const int* __restrict__ scan,
                                              const int* __restrict__ boffs,
                                              const int2* __restrict__ pair,
                                              const unsigned short* __restrict__ xl,
                                              const unsigned short* __restrict__ xr,
                                              float* __restrict__ out) {
    __shared__ __align__(16) unsigned int sXL[CEDGE * RS];   // reused as sAcc post-loop
    __shared__ __align__(16) unsigned int sXR[NPB * RS];
    __shared__ unsigned int sExP[CEDGE * HEADS];   // packed: lo<<16 | hi (bf16 bits)
    __shared__ float sExS[NPB * HEADS];
    __shared__ int   sSrc[2][CEDGE];
    __shared__ float sW[2][CEDGE];
    __shared__ int   sDst[2][CEDGE];
    __shared__ int   sStart[NPB + 1];
    __shared__ __align__(16) float sAttP[HEADS * APAD];
    __shared__ __align__(16) float sWeP[HEADS * APAD];
    __shared__ float sDen[NPB * HEADS];
    __shared__ float sWsm[NPB];

    int t = threadIdx.x;
    int h = t >> 5;                  // head for channel role (epilogue)
    int lane = t & 63;
    int wv = t >> 6;                 // wave 0..2 -> heads {2wv, 2wv+1}
    int n0 = blockIdx.x * NPB;

    // per-thread gbase/etot (uniform -> scalar loads); enables pre-sync pair load
    int gbase = boffs[n0 >> 8] + ((n0 & 255) ? scan[n0 - 1] : 0);
    int n8 = n0 + NPB;
    int gend = (n8 >= N_NODES) ? N_EDGES
             : (boffs[n8 >> 8] + ((n8 & 255) ? scan[n8 - 1] : 0));
    int etot = gend - gbase;
    int c0 = min(etot, CEDGE);

    // chunk-0 pair -> sSrc[0]/sW[0] (pre-sync)
    if (t < c0) { int2 p = pair[gbase + t]; sSrc[0][t] = p.x; sW[0][t] = __int_as_float(p.y); }

    for (int q = t; q < HEADS * APAD; q += 192) {
        int hh = q / APAD, c = q - hh * APAD;
        if (c < 32) { sAttP[q] = att[hh * 32 + c]; sWeP[q] = We[hh * 32 + c]; }
    }
    if (t <= NPB) {
        int n = n0 + t;
        int st;
        if (n >= N_NODES) st = N_EDGES;
        else {
            int b = n >> 8;
            st = boffs[b] + ((n & 255) ? scan[n - 1] : 0);
        }
        sStart[t] = st;
    }
    if (t < NPB) {   // sDst[0] pre-fill with self-computed bounds (no sStart dep)
        int n = n0 + t;
        int a = boffs[n >> 8] + ((n & 255) ? scan[n - 1] : 0);
        int n1 = n + 1;
        int b = (n1 >= N_NODES) ? N_EDGES
              : (boffs[n1 >> 8] + ((n1 & 255) ? scan[n1 - 1] : 0));
        int lo = a - gbase; if (lo < 0) lo = 0;
        int hi = b - gbase; if (hi > c0) hi = c0;
        for (int q = lo; q < hi; q++) sDst[0][q] = t;
    }
    {   // stage this block's 8 xr rows: 192 = 8 rows x 24 uint4
        int nn = t / 24, p = t - nn * 24;
        *(uint4*)&sXR[nn * RS + p * 4] = ((const uint4*)(xr + (size_t)(n0 + nn) * FEAT))[p];
    }
    __syncthreads();

    // MFMA accumulators (per wave: 2 heads x 2 channel tiles) + lane partials
    f32x4 zz = {0.f,0.f,0.f,0.f};
    f32x4 cA0 = zz, cA1 = zz, cB0 = zz, cB1 = zz;
    float denP0 = 0.f, denP1 = 0.f, wsP = 0.f;

    int nnD = t / HEADS, hhD = t - nnD * HEADS;   // self-loop ownership (t < 48)

    int nch = (etot + CEDGE - 1) / CEDGE;
    for (int ci = 0; ci < nch; ci++) {
        int i0 = ci * CEDGE;
        int c  = min(etot - i0, CEDGE);
        int cn = min(etot - i0 - CEDGE, CEDGE);   // next chunk size
        int cb = ci & 1, nb = cb ^ 1;

        // A: gather xl chunk ci -> sXL; overlap: prefetch pair ci+1 -> regs; fill sDst[nb]
        {
            int nld = c * 24;
#pragma unroll
            for (int s = 0; s < 4; s++) {
                int q = t + s * 192;
                if (q < nld) {
                    int i = q / 24, p = q - i * 24;
                    *(uint4*)&sXL[i * RS + p * 4] =
                        *(const uint4*)(xl + (size_t)sSrc[cb][i] * FEAT + p * 8);
                }
            }
        }
        int2 P;
        if (t < cn) P = pair[gbase + i0 + CEDGE + t];
        if (t < NPB && cn > 0) {
            int lo = sStart[t] - gbase - i0 - CEDGE;     if (lo < 0) lo = 0;
            int hi = sStart[t + 1] - gbase - i0 - CEDGE; if (hi > cn) hi = cn;
            for (int q = lo; q < hi; q++) sDst[nb][q] = t;
        }
        __syncthreads();

        // C: alpha + exp for chunk ci (packed hi/lo bf16); commit pair regs -> nb
        if (t < c * HEADS) {
            int i = t / HEADS, hh = t - i * HEADS;
            int nn = sDst[cb][i];
            float w = sW[cb][i];
            const uint4* pa = (const uint4*)&sXL[i * RS + hh * 16];
            const uint4* pb = (const uint4*)&sXR[nn * RS + hh * 16];
            float alpha = 0.f;
#pragma unroll
            for (int g = 0; g < 4; g++) {
                uint4 a4 = pa[g];
                uint4 b4 = pb[g];
                float4 we0 = *(const float4*)&sWeP[hh * APAD + g * 8];
                float4 we1 = *(const float4*)&sWeP[hh * APAD + g * 8 + 4];
                float4 at0 = *(const float4*)&sAttP[hh * APAD + g * 8];
                float4 at1 = *(const float4*)&sAttP[hh * APAD + g * 8 + 4];
                float wec[8] = {we0.x, we0.y, we0.z, we0.w, we1.x, we1.y, we1.z, we1.w};
                float atc[8] = {at0.x, at0.y, at0.z, at0.w, at1.x, at1.y, at1.z, at1.w};
                unsigned aw[4] = {a4.x, a4.y, a4.z, a4.w};
                unsigned bw[4] = {b4.x, b4.y, b4.z, b4.w};
#pragma unroll
                for (int q = 0; q < 4; q++) {
                    float m0 = bu2f((unsigned short)aw[q]) + bu2f((unsigned short)bw[q]) + w * wec[q * 2];
                    m0 = fmaxf(m0, NEG_SLOPE * m0);
                    alpha += m0 * atc[q * 2];
                    float m1 = bu2f((unsigned short)(aw[q] >> 16)) + bu2f((unsigned short)(bw[q] >> 16)) + w * wec[q * 2 + 1];
                    m1 = fmaxf(m1, NEG_SLOPE * m1);
                    alpha += m1 * atc[q * 2 + 1];
                }
            }
            float exv = __expf(alpha);
            unsigned short hi = f2bu(exv);
            unsigned short lo = f2bu(exv - bu2f(hi));
            sExP[t] = ((unsigned)lo << 16) | (unsigned)hi;
        }
        if (t < cn) { sSrc[nb][t] = P.x; sW[nb][t] = __int_as_float(P.y); }
        __syncthreads();

        // E: MFMA segment-sum accumulate (per wave: 2 heads); den/wsm as lane partials
        {
            const unsigned short* xlu = (const unsigned short*)sXL;
            int g8 = (lane >> 4) * 8;   // k-base of this lane's 8 elements
            int r  = lane & 15;         // A row / B col / D col
#pragma unroll
            for (int hid = 0; hid < 2; hid++) {
                int hh = wv * 2 + hid;
                short8 aHi, aLo, b0, b1;
#pragma unroll
                for (int j = 0; j < 8; j++) {
                    int i = g8 + j;
                    bool ok = (i < c);
                    unsigned u = sExP[i * HEADS + hh];   // stale-safe: gated by own/ok
                    int dd = sDst[cb][i];
                    bool own = ok && (dd == r);
                    aHi[j] = own ? (short)(u & 0xffffu) : (short)0;
                    aLo[j] = own ? (short)(u >> 16) : (short)0;
                    float exf = __uint_as_float(u << 16) + __uint_as_float(u & 0xffff0000u);
                    if (hid == 0) {
                        denP0 += own ? exf : 0.f;
                        wsP   += own ? sW[cb][i] : 0.f;
                    } else {
                        denP1 += own ? exf : 0.f;
                    }
                    int ub = i * (RS * 2) + hh * 32 + r;
                    b0[j] = ok ? (short)xlu[ub] : (short)0;
                    b1[j] = ok ? (short)xlu[ub + 16] : (short)0;
                }
                if (hid == 0) {
                    cA0 = __builtin_amdgcn_mfma_f32_16x16x32_bf16(aHi, b0, cA0, 0, 0, 0);
                    cA0 = __builtin_amdgcn_mfma_f32_16x16x32_bf16(aLo, b0, cA0, 0, 0, 0);
                    cA1 = __builtin_amdgcn_mfma_f32_16x16x32_bf16(aHi, b1, cA1, 0, 0, 0);
                    cA1 = __builtin_amdgcn_mfma_f32_16x16x32_bf16(aLo, b1, cA1, 0, 0, 0);
                } else {
                    cB0 = __builtin_amdgcn_mfma_f32_16x16x32_bf16(aHi, b0, cB0, 0, 0, 0);
                    cB0 = __builtin_amdgcn_mfma_f32_16x16x32_bf16(aLo, b0, cB0, 0, 0, 0);
                    cB1 = __builtin_amdgcn_mfma_f32_16x16x32_bf16(aHi, b1, cB1, 0, 0, 0);
                    cB1 = __builtin_amdgcn_mfma_f32_16x16x32_bf16(aLo, b1, cB1, 0, 0, 0);
                }
            }
        }
        __syncthreads();   // protects sXL/sDst/sExP overwrite next iter
    }

    // reduce lane partials over the 4 k-groups (lane^16 within half, lane^32 across)
    denP0 += __shfl_xor(denP0, 16, 64); denP0 += __shfl_xor(denP0, 32, 64);
    denP1 += __shfl_xor(denP1, 16, 64); denP1 += __shfl_xor(denP1, 32, 64);
    wsP   += __shfl_xor(wsP,   16, 64); wsP   += __shfl_xor(wsP,   32, 64);

    // dump MFMA accumulators: sAcc (aliased over sXL) + sDen + sWsm
    {
        float* sAcc = (float*)sXL;
        int rowg = lane >> 4;          // D row group
        int cc   = lane & 15;          // D col
        if (rowg < 2) {                // rows 0..7 = the 8 nodes
#pragma unroll
            for (int rg = 0; rg < 4; rg++) {
                int nn = rowg * 4 + rg;
                int h0 = wv * 2, h1 = wv * 2 + 1;
                sAcc[nn * ACS + h0 * 32 + cc]      = cA0[rg];
                sAcc[nn * ACS + h0 * 32 + 16 + cc] = cA1[rg];
                sAcc[nn * ACS + h1 * 32 + cc]      = cB0[rg];
                sAcc[nn * ACS + h1 * 32 + 16 + cc] = cB1[rg];
            }
        }
        if (lane < 8) {
            sDen[lane * HEADS + wv * 2]     = denP0;
            sDen[lane * HEADS + wv * 2 + 1] = denP1;
            if (wv == 0) sWsm[lane] = wsP;   // every wave has full data; one writes
        }
    }

    // self-loop alpha (w = mean incoming weight from sWsm); t<48 = wave 0, which
    // wrote sWsm itself -> same-wave LDS ordering, no extra barrier needed.
    if (t < NPB * HEADS) {
        int nn = nnD, hh = hhD;
        int dg = sStart[nn + 1] - sStart[nn];
        float w = sWsm[nn] / fmaxf((float)dg, 1.0f);
        const uint4* pa = (const uint4*)(xl + (size_t)(n0 + nn) * FEAT + hh * 32);
        const uint4* pb = (const uint4*)&sXR[nn * RS + hh * 16];
        float alpha = 0.f;
#pragma unroll
        for (int g = 0; g < 4; g++) {
            uint4 a4 = pa[g];
            uint4 b4 = pb[g];
            float4 we0 = *(const float4*)&sWeP[hh * APAD + g * 8];
            float4 we1 = *(const float4*)&sWeP[hh * APAD + g * 8 + 4];
            float4 at0 = *(const float4*)&sAttP[hh * APAD + g * 8];
            float4 at1 = *(const float4*)&sAttP[hh * APAD + g * 8 + 4];
            float wec[8] = {we0.x, we0.y, we0.z, we0.w, we1.x, we1.y, we1.z, we1.w};
            float atc[8] = {at0.x, at0.y, at0.z, at0.w, at1.x, at1.y, at1.z, at1.w};
            unsigned aw[4] = {a4.x, a4.y, a4.z, a4.w};
            unsigned bw[4] = {b4.x, b4.y, b4.z, b4.w};
#pragma unroll
            for (int q = 0; q < 4; q++) {
                float m0 = bu2f((unsigned short)aw[q]) + bu2f((unsigned short)bw[q]) + w * wec[q * 2];
                m0 = fmaxf(m0, NEG_SLOPE * m0);
                alpha += m0 * atc[q * 2];
                float m1 = bu2f((unsigned short)(aw[q] >> 16)) + bu2f((unsigned short)(bw[q] >> 16)) + w * wec[q * 2 + 1];
                m1 = fmaxf(m1, NEG_SLOPE * m1);
                alpha += m1 * atc[q * 2 + 1];
            }
        }
        sExS[t] = __expf(alpha);
    }
    __syncthreads();

    // epilogue: self-loop add, divide, residual + bias + relu (self xl from global)
    {
        const float* sAcc = (const float*)sXL;
        float bj = bias[t];
        float accv[NPB];
#pragma unroll
        for (int nn = 0; nn < NPB; nn++) accv[nn] = sAcc[nn * ACS + t];
#pragma unroll
        for (int nn = 0; nn < NPB; nn++) {
            float exS = sExS[nn * HEADS + h];
            size_t off = (size_t)(n0 + nn) * FEAT + t;
            float xsv = bu2f(xl[off]);
            float num = accv[nn] + exS * xsv;
            float dn  = sDen[nn * HEADS + h] + exS;
            float val = x[off] + bj + num / dn;
            out[off] = (val > 0.f) ? val : 0.f;
        }
    }
}

extern "C" void kernel_launch(void* const* d_in, const int* in_sizes, int n_in,
                              void* d_out, int out_size, void* d_ws, size_t ws_size,
                              hipStream_t stream) {
    const float* x    = (const float*)d_in[0];
    const int*   ei   = (const int*)d_in[1];
    const float* ew   = (const float*)d_in[2];
    const float* Wl   = (const float*)d_in[3];
    const float* bl   = (const float*)d_in[4];
    const float* Wr   = (const float*)d_in[5];
    const float* br   = (const float*)d_in[6];
    const float* We   = (const float*)d_in[7];
    const float* att  = (const float*)d_in[8];
    const float* bias = (const float*)d_in[9];
    float* out = (float*)d_out;

    char* ws = (char*)d_ws;
    unsigned short* xl = (unsigned short*)(ws + XL_OFF);
    unsigned short* xr = (unsigned short*)(ws + XR_OFF);
    short* Wt     = (short*)(ws + WT_OFF);
    float* blr    = (float*)(ws + BLR_OFF);
    int2*  pair   = (int2*)(ws + PAIR_OFF);
    int*   deg    = (int*)(ws + DEG_OFF);
    int*   scan   = (int*)(ws + SCAN_OFF);
    int*   bsums  = (int*)(ws + BSUM_OFF);
    int*   boffs  = (int*)(ws + BOFF_OFF);

    // zero deg; harness poisons ws with 0xAA
    hipMemsetAsync(ws + DEG_OFF, 0, N_NODES * sizeof(int), stream);

    k_count<<<(N_EDGES + 255) / 256, 256, 0, stream>>>(ei, deg, Wl, Wr, bl, br, Wt, blr);
    k_scan1<<<NB_SCAN, 256, 0, stream>>>(deg, scan, bsums);
    k_scan2<<<1, 256, 0, stream>>>(bsums, boffs);

    k_scatgemm<<<SCAT_BLOCKS + GEMM_BLOCKS, 384, 0, stream>>>(ei, ew, scan, boffs, deg,
                                                              pair, x, Wt, blr, xl, xr);

    k_node<<<N_NODES / NPB, 192, 0, stream>>>(x, bias, att, We, scan, boffs,
                                              pair, xl, xr, out);
}